// Round 18
// baseline (1157.509 us; speedup 1.0000x reference)
//
#include <hip/hip_runtime.h>

typedef unsigned short u16;
typedef signed char s8;
typedef __attribute__((ext_vector_type(4))) float f32x4;
typedef __attribute__((ext_vector_type(4))) int i32x4;

#define M_ROWS 8192
#define N_OUT  14336
#define K_IN   4096
#define NTILE  64   // K_IN / 64

__constant__ float NF4_TAB[16] = {
    -1.0f, -0.6961928009986877f, -0.5250730514526367f, -0.39491748809814453f,
    -0.28444138169288635f, -0.18477343022823334f, -0.09105003625154495f, 0.0f,
    0.07958029955625534f, 0.16093020141124725f, 0.24611230194568634f,
    0.33791524171829224f, 0.44070982933044434f, 0.5626170039176941f,
    0.7229568362236023f, 1.0f};

static __device__ __forceinline__ void async_load16(const void* g, void* l) {
  __builtin_amdgcn_global_load_lds(
      (const __attribute__((address_space(1))) void*)g,
      (__attribute__((address_space(3))) void*)l, 16, 0, 0);
}

// ---------------------------------------------------------------------------
// Merged quant kernel (verified R17): blocks [0, N_OUT) quantize W columns
// (per-column scale, R14); blocks [N_OUT, N_OUT+M_ROWS) quantize X rows
// (per-row scale, R13/R14). One launch -> HBM phases overlap.
// ---------------------------------------------------------------------------
__global__ __launch_bounds__(256) void quant_wx_kernel(
    const int* __restrict__ wp, const float* __restrict__ wa,
    s8* __restrict__ wout, float* __restrict__ sn,
    const float* __restrict__ x, s8* __restrict__ xi8,
    float* __restrict__ sxr) {
  __shared__ float red[4];
  const int t = threadIdx.x, lane = t & 63, wid = t >> 6;

  if (blockIdx.x < N_OUT) {
    // ---- W column quant ----
    const int n = blockIdx.x;
    const i32x4 p0 = __builtin_nontemporal_load(
        reinterpret_cast<const i32x4*>(wp) + (size_t)n * 512 + 2 * t);
    const i32x4 p1 = __builtin_nontemporal_load(
        reinterpret_cast<const i32x4*>(wp) + (size_t)n * 512 + 2 * t + 1);
    const float am = wa[n * 64 + (t >> 2)];

    float v[16];
    int pv[8] = {p0.x, p0.y, p0.z, p0.w, p1.x, p1.y, p1.z, p1.w};
    float mx = 0.0f;
#pragma unroll
    for (int i = 0; i < 8; ++i) {
      v[2 * i]     = NF4_TAB[(pv[i] >> 4) & 15];
      v[2 * i + 1] = NF4_TAB[pv[i] & 15];
    }
#pragma unroll
    for (int i = 0; i < 16; ++i) mx = fmaxf(mx, fabsf(v[i]));
    mx *= am;
#pragma unroll
    for (int off = 32; off; off >>= 1) mx = fmaxf(mx, __shfl_xor(mx, off));
    if (lane == 0) red[wid] = mx;
    __syncthreads();
    const float colmax = fmaxf(fmaxf(red[0], red[1]), fmaxf(red[2], red[3]));
    const float inv = colmax > 0.0f ? (127.0f * am) / colmax : 0.0f;

    union { s8 c[16]; i32x4 q; } o;
#pragma unroll
    for (int i = 0; i < 16; ++i) o.c[i] = (s8)(int)rintf(v[i] * inv);
    reinterpret_cast<i32x4*>(wout)[(size_t)n * 256 + t] = o.q;
    if (t == 0) sn[n] = colmax * (1.0f / 127.0f);
  } else {
    // ---- X row quant ----
    const int row = blockIdx.x - N_OUT;
    const float4* xr = reinterpret_cast<const float4*>(x + (size_t)row * 4096);
    float4 v[4];
    float mx = 0.0f;
#pragma unroll
    for (int i = 0; i < 4; ++i) {
      v[i] = xr[t * 4 + i];
      mx = fmaxf(mx, fmaxf(fmaxf(fabsf(v[i].x), fabsf(v[i].y)),
                           fmaxf(fabsf(v[i].z), fabsf(v[i].w))));
    }
#pragma unroll
    for (int off = 32; off; off >>= 1) mx = fmaxf(mx, __shfl_xor(mx, off));
    if (lane == 0) red[wid] = mx;
    __syncthreads();
    mx = fmaxf(fmaxf(red[0], red[1]), fmaxf(red[2], red[3]));
    float rs = mx > 0.0f ? 127.0f / mx : 0.0f;
    union { s8 c[16]; i32x4 q; } o;
#pragma unroll
    for (int i = 0; i < 4; ++i) {
      o.c[4 * i + 0] = (s8)(int)rintf(v[i].x * rs);
      o.c[4 * i + 1] = (s8)(int)rintf(v[i].y * rs);
      o.c[4 * i + 2] = (s8)(int)rintf(v[i].z * rs);
      o.c[4 * i + 3] = (s8)(int)rintf(v[i].w * rs);
    }
    reinterpret_cast<i32x4*>(xi8 + (size_t)row * 4096)[t] = o.q;
    if (t == 0) sxr[row] = mx * (1.0f / 127.0f);
  }
}

// ---------------------------------------------------------------------------
// 256x128 INT8 GEMM, mfma_i32_16x16x64_i8 (the PROVEN clean 16-row LDS
// pattern; 32-row patterns conflict irreducibly x5 trials), depth-2, one
// VM(0)+barrier per K-tile, 2 blocks/CU (launch_bounds(512,4)).
// KEY CHANGE vs R15: B is NOT staged in LDS. B fragments load DIRECTLY from
// global (XCD-L2-hot: mt-inner-8 supertile gives 8-block B-panel reuse,
// ~4MB concurrent footprint ~= L2) into double-buffered registers bFr[2][4]
// (prefetch tile s+1 during body s; ~1300 cyc MFMA cover for ~200 cyc L2
// latency). This takes ~900 cyc/tile-pair OFF the CU-wide LDS pipe (the
// measured R15 bottleneck: LDS 1920 vs MFMA 1306) -> MFMA becomes max pipe.
// Per B-load: 16 rows x one 64B line (4 kq-lanes/line) = L2-friendly.
// m-outer MFMA order keeps 1 aF live: ~110 VGPR fits the 128 cap.
// LDS: sA only, 2x16KB = 32 KB/block. Pure-i32 acc via MFMA C chain (AGPR,
// exact); scales sn[col]*sxr[row] + NF4 bias in epilogue (absmax 1.297).
// ---------------------------------------------------------------------------
__global__ __launch_bounds__(512, 4) void gemm_nf4_i8(
    const s8* __restrict__ A,    // [M][K] i8
    const s8* __restrict__ B,    // [N][K] i8
    float* __restrict__ C, const int* __restrict__ bp,
    const float* __restrict__ ba, const float* __restrict__ sn,
    const float* __restrict__ sxr) {
  constexpr int K = K_IN, N = N_OUT;
  extern __shared__ char smem[];
  char* sA = smem;                          // [2][256][64] i8 = 32 KB

  const int tid = threadIdx.x;
  const int w = tid >> 6, lane = tid & 63;
  const int r = lane & 15, kq = lane >> 4;
  const int wr = w >> 1, wc = w & 1;        // 4 x 2 wave grid, 64x64 each

  // bijective XCD swizzle (3584 % 8 == 0) + mt-inner-8 supertile
  int bid = blockIdx.x;
  int cpx = gridDim.x >> 3;                 // 448
  int wg = (bid & 7) * cpx + (bid >> 3);
  int grp = wg / 896;                       // 896 = 112 nt * 8 mt
  int rem = wg - grp * 896;
  int nt = rem >> 3;                        // 0..111
  int mt = grp * 8 + (rem & 7);             // 0..31
  const size_t m0 = (size_t)mt * 256, n0 = (size_t)nt * 128;

  const s8* gA = A + m0 * K;
  const s8* gB = B + n0 * K;

  // A read-side swizzled chunk offset (bytes); row bases multiples of 16
  const int cswz = ((kq ^ ((r >> 1) & 3)) << 4);
  // A stage-side global chunk (involution partner, R14/R15-verified)
  const int cg16 = (((lane & 3) ^ ((lane >> 3) & 3)) << 4);
  const int rl = lane >> 2;

  // hoisted stage source pointers (advance by s*64 bytes per K-tile)
  const s8* stA0 = gA + (size_t)(w * 16 + rl) * K + cg16;
  const s8* stA1 = gA + (size_t)(128 + w * 16 + rl) * K + cg16;
  // hoisted per-lane B fragment pointers (un-swizzled; direct from L2)
  const s8* gBf[4];
#pragma unroll
  for (int n_ = 0; n_ < 4; ++n_)
    gBf[n_] = gB + (size_t)(wc * 64 + n_ * 16 + r) * K + kq * 16;

  i32x4 acc[4][4] = {};        // 64 regs -> AGPRs via MFMA C chain
  i32x4 bFr[2][4];             // double-buffered B fragments (32 regs)

#define BAR() __builtin_amdgcn_s_barrier()
#define VM(n) asm volatile("s_waitcnt vmcnt(" #n ")" ::: "memory")

#define STAGE_A(P, s) do {                                                    \
    async_load16(stA0 + (size_t)(s) * 64, sA + (P) * 16384 + w * 1024);       \
    async_load16(stA1 + (size_t)(s) * 64, sA + (P) * 16384 + 8192 + w * 1024);\
  } while (0)

#define PREFETCH_B(PB, s) do {                                               \
    _Pragma("unroll")                                                        \
    for (int n_ = 0; n_ < 4; ++n_)                                           \
      bFr[PB][n_] = *reinterpret_cast<const i32x4*>(                         \
          gBf[n_] + (size_t)(s) * 64);                                       \
  } while (0)

  // m-outer: one aF live at a time (register economy); 16 MFMA/tile
#define MFMA_ALL(P) do {                                                     \
    const char* pa_ = sA + (P) * 16384 + (wr * 64 + r) * 64;                 \
    _Pragma("unroll")                                                        \
    for (int m_ = 0; m_ < 4; ++m_) {                                         \
      i32x4 aF_ = *(const i32x4*)(pa_ + m_ * 1024 + cswz);                   \
      _Pragma("unroll")                                                      \
      for (int n_ = 0; n_ < 4; ++n_)                                         \
        acc[m_][n_] = __builtin_amdgcn_mfma_i32_16x16x64_i8(                 \
            aF_, bFr[P][n_], acc[m_][n_], 0, 0, 0);                          \
    }                                                                        \
  } while (0)

  // BODY(tile s, buf P): prefetch B(s+1)->bFr[P^1], stage A(s+1)->sA[P^1],
  // then MFMA on sA[P] x bFr[P]. VM(0)+BAR at end (waits A stage; B loads
  // get the whole body + next body's latency slack via dataflow).
#define BODY(s, P, DO_NEXT, DO_VMBAR) do {                                   \
    if (DO_NEXT) { PREFETCH_B((P) ^ 1, (s) + 1); STAGE_A((P) ^ 1, (s) + 1); }\
    MFMA_ALL(P);                                                             \
    if (DO_VMBAR) { VM(0); BAR(); }                                          \
  } while (0)

  // prologue: stage A tile 0 + load B tile 0 fragments
  STAGE_A(0, 0);
  PREFETCH_B(0, 0);
  VM(0); BAR();

  for (int s = 0; s < NTILE - 2; s += 2) {
    BODY(s, 0, 1, 1);
    BODY(s + 1, 1, 1, 1);
  }
  BODY(NTILE - 2, 0, 1, 1);   // preps tile 63 (buf 1)
  BODY(NTILE - 1, 1, 0, 0);   // tail: no prefetch, no sync

  // epilogue: out = (float)acc * sn[col] * sxr[row] + bias[col]
  // C/D layout (16x16): col = lane&15, row = kq*4 + j  (R14-verified)
  float bias[4], snv[4];
#pragma unroll
  for (int ni = 0; ni < 4; ++ni) {
    int col = (int)n0 + wc * 64 + ni * 16 + r;
    int byte = bp[col >> 1];
    int code = (col & 1) ? (byte & 15) : ((byte >> 4) & 15);
    bias[ni] = NF4_TAB[code] * ba[col >> 6];
    snv[ni] = sn[col];
  }
#pragma unroll
  for (int mi = 0; mi < 4; ++mi) {
    size_t row0 = m0 + wr * 64 + mi * 16 + kq * 4;
    const f32x4 sxv = *reinterpret_cast<const f32x4*>(sxr + row0);
#pragma unroll
    for (int ni = 0; ni < 4; ++ni) {
      size_t col = n0 + wc * 64 + ni * 16 + r;
#pragma unroll
      for (int j = 0; j < 4; ++j)
        C[(row0 + j) * N + col] =
            (float)acc[mi][ni][j] * (snv[ni] * sxv[j]) + bias[ni];
    }
  }
#undef BODY
#undef MFMA_ALL
#undef PREFETCH_B
#undef STAGE_A
#undef VM
#undef BAR
}

extern "C" void kernel_launch(void* const* d_in, const int* in_sizes, int n_in,
                              void* d_out, int out_size, void* d_ws,
                              size_t ws_size, hipStream_t stream) {
  const float* x  = (const float*)d_in[0];
  const int* wp   = (const int*)d_in[1];
  const float* wa = (const float*)d_in[2];
  const int* bp   = (const int*)d_in[3];
  const float* ba = (const float*)d_in[4];
  float* out = (float*)d_out;

  // workspace layout
  s8* Wi8 = (s8*)d_ws;                                   //  58,720,256 B
  s8* Xi8 = Wi8 + (size_t)N_OUT * K_IN;                  //  33,554,432 B
  float* sn  = (float*)(Xi8 + (size_t)M_ROWS * K_IN);    //      57,344 B
  float* sxr = sn + N_OUT;                               //      32,768 B

  // merged quant: blocks [0,14336) = W cols, [14336, 22528) = X rows
  quant_wx_kernel<<<N_OUT + M_ROWS, 256, 0, stream>>>(
      wp, wa, Wi8, sn, x, Xi8, sxr);

  hipFuncSetAttribute(reinterpret_cast<const void*>(gemm_nf4_i8),
                      hipFuncAttributeMaxDynamicSharedMemorySize, 32768);
  // 32 m-tiles x 112 n-tiles
  gemm_nf4_i8<<<3584, 512, 32768, stream>>>(Xi8, Wi8, out, bp, ba, sn, sxr);
}

// Round 19
// 611.432 us; speedup vs baseline: 1.8931x; 1.8931x over previous
//
#include <hip/hip_runtime.h>

typedef unsigned short u16;
typedef signed char s8;
typedef __attribute__((ext_vector_type(4))) float f32x4;
typedef __attribute__((ext_vector_type(4))) int i32x4;

#define M_ROWS 8192
#define N_OUT  14336
#define K_IN   4096
#define NTILE  64   // K_IN / 64

__constant__ float NF4_TAB[16] = {
    -1.0f, -0.6961928009986877f, -0.5250730514526367f, -0.39491748809814453f,
    -0.28444138169288635f, -0.18477343022823334f, -0.09105003625154495f, 0.0f,
    0.07958029955625534f, 0.16093020141124725f, 0.24611230194568634f,
    0.33791524171829224f, 0.44070982933044434f, 0.5626170039176941f,
    0.7229568362236023f, 1.0f};

static __device__ __forceinline__ void async_load16(const void* g, void* l) {
  __builtin_amdgcn_global_load_lds(
      (const __attribute__((address_space(1))) void*)g,
      (__attribute__((address_space(3))) void*)l, 16, 0, 0);
}

// ---------------------------------------------------------------------------
// Merged quant kernel (verified R17): blocks [0, N_OUT) quantize W columns
// (per-column scale, R14); blocks [N_OUT, N_OUT+M_ROWS) quantize X rows
// (per-row scale, R13/R14). One launch -> the two HBM phases overlap.
// ---------------------------------------------------------------------------
__global__ __launch_bounds__(256) void quant_wx_kernel(
    const int* __restrict__ wp, const float* __restrict__ wa,
    s8* __restrict__ wout, float* __restrict__ sn,
    const float* __restrict__ x, s8* __restrict__ xi8,
    float* __restrict__ sxr) {
  __shared__ float red[4];
  const int t = threadIdx.x, lane = t & 63, wid = t >> 6;

  if (blockIdx.x < N_OUT) {
    // ---- W column quant ----
    const int n = blockIdx.x;
    const i32x4 p0 = __builtin_nontemporal_load(
        reinterpret_cast<const i32x4*>(wp) + (size_t)n * 512 + 2 * t);
    const i32x4 p1 = __builtin_nontemporal_load(
        reinterpret_cast<const i32x4*>(wp) + (size_t)n * 512 + 2 * t + 1);
    const float am = wa[n * 64 + (t >> 2)];

    float v[16];
    int pv[8] = {p0.x, p0.y, p0.z, p0.w, p1.x, p1.y, p1.z, p1.w};
    float mx = 0.0f;
#pragma unroll
    for (int i = 0; i < 8; ++i) {
      v[2 * i]     = NF4_TAB[(pv[i] >> 4) & 15];
      v[2 * i + 1] = NF4_TAB[pv[i] & 15];
    }
#pragma unroll
    for (int i = 0; i < 16; ++i) mx = fmaxf(mx, fabsf(v[i]));
    mx *= am;
#pragma unroll
    for (int off = 32; off; off >>= 1) mx = fmaxf(mx, __shfl_xor(mx, off));
    if (lane == 0) red[wid] = mx;
    __syncthreads();
    const float colmax = fmaxf(fmaxf(red[0], red[1]), fmaxf(red[2], red[3]));
    const float inv = colmax > 0.0f ? (127.0f * am) / colmax : 0.0f;

    union { s8 c[16]; i32x4 q; } o;
#pragma unroll
    for (int i = 0; i < 16; ++i) o.c[i] = (s8)(int)rintf(v[i] * inv);
    reinterpret_cast<i32x4*>(wout)[(size_t)n * 256 + t] = o.q;
    if (t == 0) sn[n] = colmax * (1.0f / 127.0f);
  } else {
    // ---- X row quant ----
    const int row = blockIdx.x - N_OUT;
    const float4* xr = reinterpret_cast<const float4*>(x + (size_t)row * 4096);
    float4 v[4];
    float mx = 0.0f;
#pragma unroll
    for (int i = 0; i < 4; ++i) {
      v[i] = xr[t * 4 + i];
      mx = fmaxf(mx, fmaxf(fmaxf(fabsf(v[i].x), fabsf(v[i].y)),
                           fmaxf(fabsf(v[i].z), fabsf(v[i].w))));
    }
#pragma unroll
    for (int off = 32; off; off >>= 1) mx = fmaxf(mx, __shfl_xor(mx, off));
    if (lane == 0) red[wid] = mx;
    __syncthreads();
    mx = fmaxf(fmaxf(red[0], red[1]), fmaxf(red[2], red[3]));
    float rs = mx > 0.0f ? 127.0f / mx : 0.0f;
    union { s8 c[16]; i32x4 q; } o;
#pragma unroll
    for (int i = 0; i < 4; ++i) {
      o.c[4 * i + 0] = (s8)(int)rintf(v[i].x * rs);
      o.c[4 * i + 1] = (s8)(int)rintf(v[i].y * rs);
      o.c[4 * i + 2] = (s8)(int)rintf(v[i].z * rs);
      o.c[4 * i + 3] = (s8)(int)rintf(v[i].w * rs);
    }
    reinterpret_cast<i32x4*>(xi8 + (size_t)row * 4096)[t] = o.q;
    if (t == 0) sxr[row] = mx * (1.0f / 127.0f);
  }
}

// ---------------------------------------------------------------------------
// 256x128 INT8 GEMM (R15 VERBATIM — best measured: 522 us, MfmaUtil 43%,
// 0 bank conflicts, no spill). mfma_i32_16x16x64_i8 (16-row LDS pattern is
// the only conflict-clean one, x5 trials), depth-2, single-phase body, one
// VM(0)+barrier per K-tile, 2 blocks/CU (launch_bounds(512,4), LDS 48KBx2).
// Per wave 64x64: acc[4][4] i32x4 in AGPRs via MFMA C chain (pure-i32 exact
// accumulation, |dot| <= 4096*127^2 < 2^31); scales sn[col]*sxr[row] + NF4
// bias applied once in the epilogue (absmax 1.297 < 2.33 threshold).
// Measured equilibrium: wall/tile = LDS pipe (1536r+375w) + MFMA (1306) --
// the pipe-sum survived 8 overlap-attempts (R6,7,8,12,16,18 + SGB + desync);
// barrier overhead is only ~116 cyc/tile. This is the HIP-level structure
// optimum for this op on gfx950.
// ---------------------------------------------------------------------------
__global__ __launch_bounds__(512, 4) void gemm_nf4_i8(
    const s8* __restrict__ A,    // [M][K] i8
    const s8* __restrict__ B,    // [N][K] i8
    float* __restrict__ C, const int* __restrict__ bp,
    const float* __restrict__ ba, const float* __restrict__ sn,
    const float* __restrict__ sxr) {
  constexpr int K = K_IN, N = N_OUT;
  extern __shared__ char smem[];
  char* sA = smem;                          // [2][256][64] i8 = 32 KB
  char* sB = smem + 32768;                  // [2][128][64] i8 = 16 KB

  const int tid = threadIdx.x;
  const int w = tid >> 6, lane = tid & 63;
  const int r = lane & 15, kq = lane >> 4;
  const int wr = w >> 1, wc = w & 1;        // 4 x 2 wave grid, 64x64 each

  // bijective XCD swizzle (3584 % 8 == 0) + mt-inner-8 supertile
  int bid = blockIdx.x;
  int cpx = gridDim.x >> 3;                 // 448
  int wg = (bid & 7) * cpx + (bid >> 3);
  int grp = wg / 896;                       // 896 = 112 nt * 8 mt
  int rem = wg - grp * 896;
  int nt = rem >> 3;                        // 0..111
  int mt = grp * 8 + (rem & 7);             // 0..31
  const size_t m0 = (size_t)mt * 256, n0 = (size_t)nt * 128;

  const s8* gA = A + m0 * K;
  const s8* gB = B + n0 * K;

  // read-side swizzled chunk offset (bytes); row bases all multiples of 16
  const int cswz = ((kq ^ ((r >> 1) & 3)) << 4);
  // stage-side global chunk (involution partner, R14/R15-verified)
  const int cg16 = (((lane & 3) ^ ((lane >> 3) & 3)) << 4);
  const int rl = lane >> 2;

  // hoisted stage source pointers (advance by s*64 bytes per K-tile)
  const s8* stA0 = gA + (size_t)(w * 16 + rl) * K + cg16;
  const s8* stA1 = gA + (size_t)(128 + w * 16 + rl) * K + cg16;
  const s8* stB0 = gB + (size_t)(w * 16 + rl) * K + cg16;

  i32x4 acc[4][4] = {};        // 64 regs -> AGPRs via MFMA C chain
  i32x4 aF[4];

#define BAR() __builtin_amdgcn_s_barrier()
#define VM(n) asm volatile("s_waitcnt vmcnt(" #n ")" ::: "memory")

#define STAGE_AB(P, s) do {                                                   \
    async_load16(stA0 + (size_t)(s) * 64, sA + (P) * 16384 + w * 1024);       \
    async_load16(stA1 + (size_t)(s) * 64, sA + (P) * 16384 + 8192 + w * 1024);\
    async_load16(stB0 + (size_t)(s) * 64, sB + (P) * 8192 + w * 1024);        \
  } while (0)

#define READ_A(P) do {                                                       \
    const char* pa_ = sA + (P) * 16384 + (wr * 64 + r) * 64;                 \
    _Pragma("unroll")                                                        \
    for (int m_ = 0; m_ < 4; ++m_)                                           \
      aF[m_] = *(const i32x4*)(pa_ + m_ * 1024 + cswz);                      \
  } while (0)

  // stream one B fragment at a time (4 live VGPRs), 4 MFMA per fragment
#define MFMA_ALL(P) do {                                                     \
    const char* pb_ = sB + (P) * 8192 + (wc * 64 + r) * 64;                  \
    __builtin_amdgcn_s_setprio(1);                                           \
    _Pragma("unroll")                                                        \
    for (int n_ = 0; n_ < 4; ++n_) {                                         \
      i32x4 bF_ = *(const i32x4*)(pb_ + n_ * 1024 + cswz);                   \
      _Pragma("unroll")                                                      \
      for (int m_ = 0; m_ < 4; ++m_)                                         \
        acc[m_][n_] = __builtin_amdgcn_mfma_i32_16x16x64_i8(                 \
            aF[m_], bF_, acc[m_][n_], 0, 0, 0);                              \
    }                                                                        \
    __builtin_amdgcn_s_setprio(0);                                           \
  } while (0)

#define BODY(s, P, DO_STAGE, DO_VMBAR) do {                                  \
    READ_A(P);                                                               \
    if (DO_STAGE) STAGE_AB((P) ^ 1, (s) + 1);                                \
    MFMA_ALL(P);                                                             \
    if (DO_VMBAR) { VM(0); BAR(); }                                          \
  } while (0)

  // prologue: stage tile 0 into buf[0]
  STAGE_AB(0, 0);
  VM(0); BAR();

  for (int s = 0; s < NTILE - 2; s += 2) {
    BODY(s, 0, 1, 1);
    BODY(s + 1, 1, 1, 1);
  }
  BODY(NTILE - 2, 0, 1, 1);   // stages tile 63 into buf[1]
  BODY(NTILE - 1, 1, 0, 0);   // tail: no stage, no sync

  // epilogue: out = (float)acc * sn[col] * sxr[row] + bias[col]
  // C/D layout (16x16): col = lane&15, row = kq*4 + j  (R14-verified)
  float bias[4], snv[4];
#pragma unroll
  for (int ni = 0; ni < 4; ++ni) {
    int col = (int)n0 + wc * 64 + ni * 16 + r;
    int byte = bp[col >> 1];
    int code = (col & 1) ? (byte & 15) : ((byte >> 4) & 15);
    bias[ni] = NF4_TAB[code] * ba[col >> 6];
    snv[ni] = sn[col];
  }
#pragma unroll
  for (int mi = 0; mi < 4; ++mi) {
    size_t row0 = m0 + wr * 64 + mi * 16 + kq * 4;
    const f32x4 sxv = *reinterpret_cast<const f32x4*>(sxr + row0);
#pragma unroll
    for (int ni = 0; ni < 4; ++ni) {
      size_t col = n0 + wc * 64 + ni * 16 + r;
#pragma unroll
      for (int j = 0; j < 4; ++j)
        C[(row0 + j) * N + col] =
            (float)acc[mi][ni][j] * (snv[ni] * sxv[j]) + bias[ni];
    }
  }
#undef BODY
#undef MFMA_ALL
#undef READ_A
#undef STAGE_AB
#undef VM
#undef BAR
}

extern "C" void kernel_launch(void* const* d_in, const int* in_sizes, int n_in,
                              void* d_out, int out_size, void* d_ws,
                              size_t ws_size, hipStream_t stream) {
  const float* x  = (const float*)d_in[0];
  const int* wp   = (const int*)d_in[1];
  const float* wa = (const float*)d_in[2];
  const int* bp   = (const int*)d_in[3];
  const float* ba = (const float*)d_in[4];
  float* out = (float*)d_out;

  // workspace layout
  s8* Wi8 = (s8*)d_ws;                                   //  58,720,256 B
  s8* Xi8 = Wi8 + (size_t)N_OUT * K_IN;                  //  33,554,432 B
  float* sn  = (float*)(Xi8 + (size_t)M_ROWS * K_IN);    //      57,344 B
  float* sxr = sn + N_OUT;                               //      32,768 B

  // merged quant: blocks [0,14336) = W cols, [14336, 22528) = X rows
  quant_wx_kernel<<<N_OUT + M_ROWS, 256, 0, stream>>>(
      wp, wa, Wi8, sn, x, Xi8, sxr);

  hipFuncSetAttribute(reinterpret_cast<const void*>(gemm_nf4_i8),
                      hipFuncAttributeMaxDynamicSharedMemorySize, 49152);
  // 32 m-tiles x 112 n-tiles
  gemm_nf4_i8<<<3584, 512, 49152, stream>>>(Xi8, Wi8, out, bp, ba, sn, sxr);
}